// Round 1
// baseline (301.631 us; speedup 1.0000x reference)
//
#include <hip/hip_runtime.h>

#define NTOT  16384
#define NFEAT 300
#define NHID  512
#define NOUT  256
#define NACT  64
#define NEIGH 2048
#define SSZ   2112   // NACT + NEIGH

// ---------------------------------------------------------------- build cur
__global__ void k_build(const int* __restrict__ act, const int* __restrict__ nb,
                        int* __restrict__ cur, float* __restrict__ out_nb) {
    int i = blockIdx.x * 256 + threadIdx.x;
    if (i < SSZ)  cur[i] = (i < NACT) ? act[i] : nb[i - NACT];
    if (i < NEIGH) out_nb[i] = (float)nb[i];   // neighbor_idx as float, exact
}

// ------------------------------------------------- adjacency scan -> sparse
// One block per subgraph row. Two-pass ordered compaction (deterministic):
// pass 1 counts per-thread nnz over a contiguous j-chunk, serial prefix sum,
// pass 2 re-reads (L1/L2 hit) and writes column indices in j-order.
__global__ __launch_bounds__(256) void k_scan(const float* __restrict__ adj,
                                              const int* __restrict__ cur,
                                              int* __restrict__ cnt,
                                              unsigned short* __restrict__ cols) {
    __shared__ int scur[SSZ];
    __shared__ int tpre[257];
    int t = threadIdx.x;
    for (int k = t; k < SSZ; k += 256) scur[k] = cur[k];
    __syncthreads();

    int row = blockIdx.x;
    long long base = (long long)scur[row] * NTOT;
    int j0 = t * 9;                       // ceil(2112/256) = 9
    int j1 = min(j0 + 9, SSZ);

    int c = 0;
    for (int j = j0; j < j1; ++j)
        c += (adj[base + scur[j]] != 0.0f) ? 1 : 0;
    tpre[t + 1] = c;
    __syncthreads();
    if (t == 0) {
        tpre[0] = 0;
        for (int k = 1; k <= 256; ++k) tpre[k] += tpre[k - 1];
        cnt[row] = tpre[256];
    }
    __syncthreads();

    int off = tpre[t];
    unsigned short* dst = cols + (size_t)row * SSZ;
    for (int j = j0; j < j1; ++j)
        if (adj[base + scur[j]] != 0.0f) dst[off++] = (unsigned short)j;
}

// ------------------------------------------------------------- dense GEMM
// C[M x Nn] = A[M x K] @ B[K x Nn]; optional row-gather on A via rowidx.
// 64x64 tile per 256-thread block, 4x4 microtile, K-tile 16.
__global__ __launch_bounds__(256) void k_gemm(const float* __restrict__ A,
                                              const float* __restrict__ B,
                                              float* __restrict__ C,
                                              int M, int Nn, int K,
                                              const int* __restrict__ rowidx) {
    __shared__ float As[16][68];   // +4 pad: conflict-free transposed store,
                                   // 16B-aligned float4 rows (68*4 % 16 == 0)
    __shared__ float Bs[16][64];
    int tid = threadIdx.x;
    int tx = tid & 15, ty = tid >> 4;
    int bm = blockIdx.x * 64;
    int bn = blockIdx.y * 64;

    float acc[4][4] = {};

    for (int kt = 0; kt < K; kt += 16) {
#pragma unroll
        for (int l = 0; l < 4; ++l) {          // A tile: 64 rows x 16 k
            int idx = tid + l * 256;
            int m = idx >> 4, kk = idx & 15;
            int gk = kt + kk;
            int gm = bm + m;
            int ar = rowidx ? rowidx[gm] : gm;
            As[kk][m] = (gk < K) ? A[(long long)ar * K + gk] : 0.0f;
        }
#pragma unroll
        for (int l = 0; l < 4; ++l) {          // B tile: 16 k x 64 n
            int idx = tid + l * 256;
            int nn = idx & 63, kk = idx >> 6;
            int gk = kt + kk;
            Bs[kk][nn] = (gk < K) ? B[(long long)gk * Nn + bn + nn] : 0.0f;
        }
        __syncthreads();
#pragma unroll
        for (int kk = 0; kk < 16; ++kk) {
            float4 av = *(const float4*)&As[kk][ty * 4];
            float4 bv = *(const float4*)&Bs[kk][tx * 4];
            float a[4] = {av.x, av.y, av.z, av.w};
            float b[4] = {bv.x, bv.y, bv.z, bv.w};
#pragma unroll
            for (int r = 0; r < 4; ++r)
#pragma unroll
                for (int cc = 0; cc < 4; ++cc)
                    acc[r][cc] += a[r] * b[cc];
        }
        __syncthreads();
    }
#pragma unroll
    for (int r = 0; r < 4; ++r) {
        int gm = bm + ty * 4 + r;
        float4 v = make_float4(acc[r][0], acc[r][1], acc[r][2], acc[r][3]);
        *(float4*)&C[(long long)gm * Nn + bn + tx * 4] = v;
    }
}

// --------------------------------------------------------------- sparse MM
// Out[row][:] = sum_{j in nnz(row)} Mtx[j][:]   (A entries are exactly 1.0)
template <int C, bool RELU>
__global__ __launch_bounds__(256) void k_spmm(const float* __restrict__ Mtx,
                                              const int* __restrict__ cnt,
                                              const unsigned short* __restrict__ cols,
                                              float* __restrict__ Out) {
    int row = blockIdx.x;
    int t = threadIdx.x;
    int n = cnt[row];
    const unsigned short* cl = cols + (size_t)row * SSZ;
    float acc[C / 256];
#pragma unroll
    for (int i = 0; i < C / 256; ++i) acc[i] = 0.0f;
    for (int k = 0; k < n; ++k) {
        int j = cl[k];
#pragma unroll
        for (int i = 0; i < C / 256; ++i)
            acc[i] += Mtx[(size_t)j * C + t + i * 256];
    }
#pragma unroll
    for (int i = 0; i < C / 256; ++i) {
        float v = acc[i];
        if (RELU) v = fmaxf(v, 0.0f);
        Out[(size_t)row * C + t + i * 256] = v;
    }
}

// ------------------------------------------------------- importance scores
__global__ __launch_bounds__(256) void k_imp(const float* __restrict__ T3,
                                             const float* __restrict__ w,
                                             const float* __restrict__ b,
                                             float* __restrict__ imp) {
    int row = blockIdx.x;
    int t = threadIdx.x;                 // 256 == NOUT
    float v = T3[(size_t)row * NOUT + t] * w[t];
    __shared__ float wsum[4];
#pragma unroll
    for (int o = 32; o > 0; o >>= 1) v += __shfl_down(v, o, 64);
    if ((t & 63) == 0) wsum[t >> 6] = v;
    __syncthreads();
    if (t == 0) imp[row] = wsum[0] + wsum[1] + wsum[2] + wsum[3] + b[0];
}

// --------------------------------------------------- L1 normalize + output
__global__ __launch_bounds__(256) void k_finish(const float* __restrict__ imp,
                                                float* __restrict__ out) {
    int t = threadIdx.x;
    __shared__ float wsum[4];
    __shared__ float inv;
    float s = 0.0f;
    for (int i = t; i < SSZ; i += 256) s += fabsf(imp[i]);
#pragma unroll
    for (int o = 32; o > 0; o >>= 1) s += __shfl_down(s, o, 64);
    if ((t & 63) == 0) wsum[t >> 6] = s;
    __syncthreads();
    if (t == 0) inv = 1.0f / fmaxf(wsum[0] + wsum[1] + wsum[2] + wsum[3], 1e-12f);
    __syncthreads();
    for (int i = t; i < NEIGH; i += 256) out[i] = imp[NACT + i] * inv;
}

// --------------------------------------------------------------------------
extern "C" void kernel_launch(void* const* d_in, const int* in_sizes, int n_in,
                              void* d_out, int out_size, void* d_ws, size_t ws_size,
                              hipStream_t stream) {
    const float* x   = (const float*)d_in[0];
    const float* adj = (const float*)d_in[1];
    const int*   act = (const int*)d_in[2];
    const int*   nb  = (const int*)d_in[3];
    const float* W1  = (const float*)d_in[4];
    const float* W2  = (const float*)d_in[5];
    const float* iw  = (const float*)d_in[6];
    const float* ib  = (const float*)d_in[7];
    float* out = (float*)d_out;

    // workspace layout (bytes, 256-aligned) — total ~24.1 MB
    char* ws = (char*)d_ws;
    int*            cur  = (int*)           (ws + 0);         //  8448 B
    int*            cnt  = (int*)           (ws + 8704);      //  8448 B
    unsigned short* cols = (unsigned short*)(ws + 17408);     //  8.92 MB
    float*          B1   = (float*)         (ws + 8938496);   //  4.33 MB  X@W1
    float*          H1   = (float*)         (ws + 13263872);  //  4.33 MB  relu(A@B1)
    float*          B2   = (float*)         (ws + 17589248);  //  2.16 MB  H1@W2
    float*          H2   = (float*)         (ws + 19751936);  //  2.16 MB  A@B2
    float*          T3   = (float*)         (ws + 21914624);  //  2.16 MB  A@H2
    float*          imp  = (float*)         (ws + 24077312);  //  8448 B

    k_build <<<dim3((SSZ + 255) / 256), 256, 0, stream>>>(act, nb, cur, out + NEIGH);
    k_scan  <<<dim3(SSZ),              256, 0, stream>>>(adj, cur, cnt, cols);
    k_gemm  <<<dim3(33, 8),            256, 0, stream>>>(x,  W1, B1, SSZ, NHID, NFEAT, cur);
    k_spmm<NHID, true>  <<<dim3(SSZ),  256, 0, stream>>>(B1, cnt, cols, H1);
    k_gemm  <<<dim3(33, 4),            256, 0, stream>>>(H1, W2, B2, SSZ, NOUT, NHID, nullptr);
    k_spmm<NOUT, false> <<<dim3(SSZ),  256, 0, stream>>>(B2, cnt, cols, H2);
    k_spmm<NOUT, false> <<<dim3(SSZ),  256, 0, stream>>>(H2, cnt, cols, T3);
    k_imp   <<<dim3(SSZ),              256, 0, stream>>>(T3, iw, ib, imp);
    k_finish<<<dim3(1),                256, 0, stream>>>(imp, out);
}

// Round 2
// 156.199 us; speedup vs baseline: 1.9311x; 1.9311x over previous
//
#include <hip/hip_runtime.h>

#define NTOT  16384
#define NFEAT 300
#define NHID  512
#define NOUT  256
#define NACT  64
#define NEIGH 2048
#define SSZ   2112   // NACT + NEIGH

// --------------------------------------------------------------- prep
// grid 9 x 256: build cur[], write neighbor_idx floats to out tail, and
// compute u = W2 @ imp_w (512-vector) spread over the 36 waves.
__global__ __launch_bounds__(256) void k_prep(const int* __restrict__ act,
                                              const int* __restrict__ nb,
                                              const float* __restrict__ W2,
                                              const float* __restrict__ iw,
                                              int* __restrict__ cur,
                                              float* __restrict__ u,
                                              float* __restrict__ out_nb) {
    int t = threadIdx.x;
    int i = blockIdx.x * 256 + t;
    if (i < SSZ)  cur[i] = (i < NACT) ? act[i] : nb[i - NACT];
    if (i < NEIGH) out_nb[i] = (float)nb[i];

    int gw = blockIdx.x * 4 + (t >> 6);       // global wave id, 0..35
    int lane = t & 63;
    for (int r = gw; r < NHID; r += 36) {     // u[r] = dot(W2[r,:], iw)
        float p = 0.0f;
#pragma unroll
        for (int q = 0; q < 4; ++q)
            p += W2[(size_t)r * NOUT + lane + q * 64] * iw[lane + q * 64];
#pragma unroll
        for (int o = 32; o > 0; o >>= 1) p += __shfl_down(p, o, 64);
        if (lane == 0) u[r] = p;
    }
}

// --------------------------------------------------------------- scan
// One block per subgraph row: ordered two-pass compaction of nnz columns.
// Lane-consecutive j (j = t + 256k) -> adjacent lanes hit adjacent columns
// (~2 cols per 64B line). Parallel Hillis-Steele prefix instead of serial.
__global__ __launch_bounds__(256) void k_scan(const float* __restrict__ adj,
                                              const int* __restrict__ act,
                                              const int* __restrict__ nb,
                                              int* __restrict__ cnt,
                                              unsigned short* __restrict__ cols) {
    __shared__ int scur[SSZ];
    __shared__ int tsum[256];
    int t = threadIdx.x;
    for (int k = t; k < SSZ; k += 256)
        scur[k] = (k < NACT) ? act[k] : nb[k - NACT];
    __syncthreads();

    int row = blockIdx.x;
    const float* arow = adj + (size_t)scur[row] * NTOT;

    int c = 0;
#pragma unroll
    for (int k = 0; k < 9; ++k) {
        int j = t + (k << 8);
        if (j < SSZ && arow[scur[j]] != 0.0f) ++c;
    }
    tsum[t] = c;
    __syncthreads();
#pragma unroll
    for (int off = 1; off < 256; off <<= 1) {   // inclusive scan, 8 steps
        int x = (t >= off) ? tsum[t - off] : 0;
        __syncthreads();
        tsum[t] += x;
        __syncthreads();
    }
    if (t == 255) cnt[row] = tsum[255];

    int off = tsum[t] - c;                      // exclusive offset
    unsigned short* dst = cols + (size_t)row * SSZ;
#pragma unroll
    for (int k = 0; k < 9; ++k) {
        int j = t + (k << 8);
        if (j < SSZ && arow[scur[j]] != 0.0f) dst[off++] = (unsigned short)j;
    }
}

// --------------------------------------------------------------- GEMM
// C[M x Nn] = A[M x K] @ B[K x Nn], optional row gather on A.
// 32x64 tile / 256 threads / 2x4 microtile -> 528 blocks = 2 per CU.
__global__ __launch_bounds__(256) void k_gemm(const float* __restrict__ A,
                                              const float* __restrict__ B,
                                              float* __restrict__ C,
                                              int M, int Nn, int K,
                                              const int* __restrict__ rowidx) {
    __shared__ float As[16][36];   // +4 pad
    __shared__ float Bs[16][64];
    int tid = threadIdx.x;
    int tx = tid & 15, ty = tid >> 4;
    int bm = blockIdx.x * 32, bn = blockIdx.y * 64;
    float acc[2][4] = {};

    for (int kt = 0; kt < K; kt += 16) {
#pragma unroll
        for (int l = 0; l < 2; ++l) {          // A tile: 32 rows x 16 k
            int idx = tid + l * 256;
            int m = idx >> 4, kk = idx & 15;
            int gk = kt + kk, gm = bm + m;
            int ar = rowidx ? rowidx[gm] : gm;
            As[kk][m] = (gk < K) ? A[(size_t)ar * K + gk] : 0.0f;
        }
#pragma unroll
        for (int l = 0; l < 4; ++l) {          // B tile: 16 k x 64 n
            int idx = tid + l * 256;
            int nn = idx & 63, kk = idx >> 6;
            int gk = kt + kk;
            Bs[kk][nn] = (gk < K) ? B[(size_t)gk * Nn + bn + nn] : 0.0f;
        }
        __syncthreads();
#pragma unroll
        for (int kk = 0; kk < 16; ++kk) {
            float a0 = As[kk][ty * 2], a1 = As[kk][ty * 2 + 1];
            float4 bv = *(const float4*)&Bs[kk][tx * 4];
            acc[0][0] += a0 * bv.x; acc[0][1] += a0 * bv.y;
            acc[0][2] += a0 * bv.z; acc[0][3] += a0 * bv.w;
            acc[1][0] += a1 * bv.x; acc[1][1] += a1 * bv.y;
            acc[1][2] += a1 * bv.z; acc[1][3] += a1 * bv.w;
        }
        __syncthreads();
    }
#pragma unroll
    for (int r = 0; r < 2; ++r) {
        int gm = bm + ty * 2 + r;
        *(float4*)&C[(size_t)gm * Nn + bn + tx * 4] =
            make_float4(acc[r][0], acc[r][1], acc[r][2], acc[r][3]);
    }
}

// --------------------------------------------------------------- fused spMV
// v[row] = dot(relu(sum_{j in nnz(row)} B1[j,:]), u)   -- H1 never stored
__global__ __launch_bounds__(256) void k_spmv(const float* __restrict__ B1,
                                              const int* __restrict__ cnt,
                                              const unsigned short* __restrict__ cols,
                                              const float* __restrict__ u,
                                              float* __restrict__ v) {
    __shared__ float su[NHID];
    __shared__ float wsum[4];
    int t = threadIdx.x, row = blockIdx.x;
    su[t] = u[t]; su[t + 256] = u[t + 256];

    int n = cnt[row];
    const unsigned short* cl = cols + (size_t)row * SSZ;
    float a0 = 0.0f, a1 = 0.0f;
    for (int k = 0; k < n; ++k) {
        int j = cl[k];
        a0 += B1[(size_t)j * NHID + t];
        a1 += B1[(size_t)j * NHID + t + 256];
    }
    __syncthreads();
    float p = fmaxf(a0, 0.0f) * su[t] + fmaxf(a1, 0.0f) * su[t + 256];
#pragma unroll
    for (int o = 32; o > 0; o >>= 1) p += __shfl_down(p, o, 64);
    if ((t & 63) == 0) wsum[t >> 6] = p;
    __syncthreads();
    if (t == 0) v[row] = wsum[0] + wsum[1] + wsum[2] + wsum[3];
}

// --------------------------------------------------------------- final
// Single block: s1 = A@v, s2 = A@s1 + b, L1-normalize, emit imp[NACT:].
__global__ __launch_bounds__(256) void k_final(const int* __restrict__ cnt,
                                               const unsigned short* __restrict__ cols,
                                               const float* __restrict__ v,
                                               const float* __restrict__ ib,
                                               float* __restrict__ out) {
    __shared__ float sv[SSZ];
    __shared__ float s1[SSZ];
    __shared__ float s2[SSZ];
    __shared__ int   sc[SSZ];
    __shared__ float wsum[4];
    __shared__ float inv;
    int t = threadIdx.x;
    for (int i = t; i < SSZ; i += 256) { sv[i] = v[i]; sc[i] = cnt[i]; }
    __syncthreads();
    for (int i = t; i < SSZ; i += 256) {
        const unsigned short* cl = cols + (size_t)i * SSZ;
        int n = sc[i];
        float s = 0.0f;
        for (int k = 0; k < n; ++k) s += sv[cl[k]];
        s1[i] = s;
    }
    __syncthreads();
    for (int i = t; i < SSZ; i += 256) {
        const unsigned short* cl = cols + (size_t)i * SSZ;
        int n = sc[i];
        float s = 0.0f;
        for (int k = 0; k < n; ++k) s += s1[cl[k]];
        s2[i] = s + ib[0];
    }
    __syncthreads();
    float s = 0.0f;
    for (int i = t; i < SSZ; i += 256) s += fabsf(s2[i]);
#pragma unroll
    for (int o = 32; o > 0; o >>= 1) s += __shfl_down(s, o, 64);
    if ((t & 63) == 0) wsum[t >> 6] = s;
    __syncthreads();
    if (t == 0) inv = 1.0f / fmaxf(wsum[0] + wsum[1] + wsum[2] + wsum[3], 1e-12f);
    __syncthreads();
    for (int i = t; i < NEIGH; i += 256) out[i] = s2[NACT + i] * inv;
}

// --------------------------------------------------------------------------
extern "C" void kernel_launch(void* const* d_in, const int* in_sizes, int n_in,
                              void* d_out, int out_size, void* d_ws, size_t ws_size,
                              hipStream_t stream) {
    const float* x   = (const float*)d_in[0];
    const float* adj = (const float*)d_in[1];
    const int*   act = (const int*)d_in[2];
    const int*   nb  = (const int*)d_in[3];
    const float* W1  = (const float*)d_in[4];
    const float* W2  = (const float*)d_in[5];
    const float* iw  = (const float*)d_in[6];
    const float* ib  = (const float*)d_in[7];
    float* out = (float*)d_out;

    // workspace layout (bytes, 256-aligned) — total ~13.3 MB
    char* ws = (char*)d_ws;
    int*            cur  = (int*)           (ws + 0);         // 8448 B
    int*            cnt  = (int*)           (ws + 8704);      // 8448 B
    unsigned short* cols = (unsigned short*)(ws + 17408);     // 8.92 MB
    float*          B1   = (float*)         (ws + 8938496);   // 4.33 MB  X[cur]@W1
    float*          u    = (float*)         (ws + 13263872);  // 2048 B   W2@imp_w
    float*          v    = (float*)         (ws + 13266176);  // 8448 B   H1@u

    k_prep <<<dim3(9),     256, 0, stream>>>(act, nb, W2, iw, cur, u, out + NEIGH);
    k_scan <<<dim3(SSZ),   256, 0, stream>>>(adj, act, nb, cnt, cols);
    k_gemm <<<dim3(66, 8), 256, 0, stream>>>(x, W1, B1, SSZ, NHID, NFEAT, cur);
    k_spmv <<<dim3(SSZ),   256, 0, stream>>>(B1, cnt, cols, u, v);
    k_final<<<dim3(1),     256, 0, stream>>>(cnt, cols, v, ib, out);
}

// Round 3
// 111.600 us; speedup vs baseline: 2.7028x; 1.3996x over previous
//
#include <hip/hip_runtime.h>

#define NTOT  16384
#define NFEAT 300
#define NHID  512
#define NOUT  256
#define NACT  64
#define NEIGH 2048
#define SSZ   2112   // NACT + NEIGH
#define CSTR  64     // cols row stride (max nnz/row ~4.2 mean, 64 = ~30 sigma)

// --------------------------------------------------------------- scan (+prep)
// One block per subgraph row. Single pass: 9 unconditional scattered loads per
// thread (max MLP), ballot -> 36 group masks -> one wave-level shfl prefix ->
// ordered compaction. 2 barriers total. Blocks 0..8 also do the prep chores
// (cur[], neighbor floats to out tail, u = W2 @ imp_w).
__global__ __launch_bounds__(256) void k_scan(const float* __restrict__ adj,
                                              const int* __restrict__ act,
                                              const int* __restrict__ nb,
                                              const float* __restrict__ W2,
                                              const float* __restrict__ iw,
                                              int* __restrict__ cnt,
                                              unsigned short* __restrict__ cols,
                                              int* __restrict__ cur,
                                              float* __restrict__ u,
                                              float* __restrict__ out_nb) {
    __shared__ int scur[2304];                 // padded to 9*256
    __shared__ unsigned long long smask[9][4];
    __shared__ int spre[37];
    int t = threadIdx.x;
    int w = t >> 6, lane = t & 63;
    for (int k = t; k < 2304; k += 256)
        scur[k] = (k < NACT) ? act[k] : (k < SSZ ? nb[k - NACT] : 0);
    __syncthreads();

    int row = blockIdx.x;
    const float* arow = adj + (size_t)scur[row] * NTOT;

    // all 9 loads issued unconditionally (pad cols read arow[0], discarded)
    float val[9];
#pragma unroll
    for (int k = 0; k < 9; ++k) val[k] = arow[scur[t + (k << 8)]];

    bool hit[9];
#pragma unroll
    for (int k = 0; k < 9; ++k) {
        int j = t + (k << 8);
        hit[k] = (j < SSZ) && (val[k] != 0.0f);
        unsigned long long m = __ballot(hit[k]);
        if (lane == 0) smask[k][w] = m;
    }

    // ---- prep chores on blocks 0..8 (before barrier; independent of smask)
    if (row < 9) {
        int i = row * 256 + t;
        if (row == 0) for (int k = t; k < SSZ; k += 256) cur[k] = scur[k];
        if (i < NEIGH) out_nb[i] = (float)nb[i];
        int r0 = row * 4 + w;                   // global wave id 0..35
        for (int r = r0; r < NHID; r += 36) {   // u[r] = dot(W2[r,:], iw)
            float p = 0.0f;
#pragma unroll
            for (int q = 0; q < 4; ++q)
                p += W2[(size_t)r * NOUT + lane + q * 64] * iw[lane + q * 64];
#pragma unroll
            for (int o = 32; o > 0; o >>= 1) p += __shfl_down(p, o, 64);
            if (lane == 0) u[r] = p;
        }
    }
    __syncthreads();

    // ---- exclusive prefix over the 36 (chunk,wave) groups, in wave 0
    if (t < 64) {
        int c = (t < 36) ? __popcll(smask[t >> 2][t & 3]) : 0;
        int v = c;
#pragma unroll
        for (int o = 1; o < 64; o <<= 1) {
            int x = __shfl_up(v, o, 64);
            if (lane >= o) v += x;
        }
        if (t == 0) spre[0] = 0;
        if (t < 36) spre[t + 1] = v;
    }
    __syncthreads();

    unsigned short* dst = cols + (size_t)row * CSTR;
#pragma unroll
    for (int k = 0; k < 9; ++k) {
        if (hit[k]) {
            unsigned long long below = smask[k][w] & ((1ull << lane) - 1ull);
            int off = spre[k * 4 + w] + __popcll(below);
            dst[off] = (unsigned short)(t + (k << 8));
        }
    }
    if (t == 0) cnt[row] = spre[36];
}

// --------------------------------------------------------------- GEMM
// C[M x Nn] = A[M x K] @ B[K x Nn], row gather on A via rowidx.
// 32x64 tile / 256 threads / 2x4 microtile -> 528 blocks = 2 per CU.
__global__ __launch_bounds__(256) void k_gemm(const float* __restrict__ A,
                                              const float* __restrict__ B,
                                              float* __restrict__ C,
                                              int M, int Nn, int K,
                                              const int* __restrict__ rowidx) {
    __shared__ float As[16][36];
    __shared__ float Bs[16][64];
    int tid = threadIdx.x;
    int tx = tid & 15, ty = tid >> 4;
    int bm = blockIdx.x * 32, bn = blockIdx.y * 64;
    float acc[2][4] = {};

    for (int kt = 0; kt < K; kt += 16) {
#pragma unroll
        for (int l = 0; l < 2; ++l) {
            int idx = tid + l * 256;
            int m = idx >> 4, kk = idx & 15;
            int gk = kt + kk, gm = bm + m;
            int ar = rowidx ? rowidx[gm] : gm;
            As[kk][m] = (gk < K) ? A[(size_t)ar * K + gk] : 0.0f;
        }
#pragma unroll
        for (int l = 0; l < 4; ++l) {
            int idx = tid + l * 256;
            int nn = idx & 63, kk = idx >> 6;
            int gk = kt + kk;
            Bs[kk][nn] = (gk < K) ? B[(size_t)gk * Nn + bn + nn] : 0.0f;
        }
        __syncthreads();
#pragma unroll
        for (int kk = 0; kk < 16; ++kk) {
            float a0 = As[kk][ty * 2], a1 = As[kk][ty * 2 + 1];
            float4 bv = *(const float4*)&Bs[kk][tx * 4];
            acc[0][0] += a0 * bv.x; acc[0][1] += a0 * bv.y;
            acc[0][2] += a0 * bv.z; acc[0][3] += a0 * bv.w;
            acc[1][0] += a1 * bv.x; acc[1][1] += a1 * bv.y;
            acc[1][2] += a1 * bv.z; acc[1][3] += a1 * bv.w;
        }
        __syncthreads();
    }
#pragma unroll
    for (int r = 0; r < 2; ++r) {
        int gm = bm + ty * 2 + r;
        *(float4*)&C[(size_t)gm * Nn + bn + tx * 4] =
            make_float4(acc[r][0], acc[r][1], acc[r][2], acc[r][3]);
    }
}

// --------------------------------------------------------------- fused spMV
// v[row] = dot(relu(sum_{j in nnz(row)} B1[j,:]), u)
__global__ __launch_bounds__(256) void k_spmv(const float* __restrict__ B1,
                                              const int* __restrict__ cnt,
                                              const unsigned short* __restrict__ cols,
                                              const float* __restrict__ u,
                                              float* __restrict__ v) {
    __shared__ float su[NHID];
    __shared__ float wsum[4];
    int t = threadIdx.x, row = blockIdx.x;
    su[t] = u[t]; su[t + 256] = u[t + 256];

    int n = cnt[row];
    const unsigned short* cl = cols + (size_t)row * CSTR;
    float a0 = 0.0f, a1 = 0.0f;
    for (int k = 0; k < n; ++k) {
        int j = cl[k];
        a0 += B1[(size_t)j * NHID + t];
        a1 += B1[(size_t)j * NHID + t + 256];
    }
    __syncthreads();
    float p = fmaxf(a0, 0.0f) * su[t] + fmaxf(a1, 0.0f) * su[t + 256];
#pragma unroll
    for (int o = 32; o > 0; o >>= 1) p += __shfl_down(p, o, 64);
    if ((t & 63) == 0) wsum[t >> 6] = p;
    __syncthreads();
    if (t == 0) v[row] = wsum[0] + wsum[1] + wsum[2] + wsum[3];
}

// --------------------------------------------------------------- final
// Single block, 1024 threads: s1 = A@v, s2 = A@s1 + b, L1 norm, out.
__global__ __launch_bounds__(1024) void k_final(const int* __restrict__ cnt,
                                                const unsigned short* __restrict__ cols,
                                                const float* __restrict__ v,
                                                const float* __restrict__ ib,
                                                float* __restrict__ out) {
    __shared__ float sv[SSZ];
    __shared__ float s1[SSZ];
    __shared__ float s2[SSZ];
    __shared__ int   sc[SSZ];
    __shared__ float wsum[16];
    __shared__ float inv;
    int t = threadIdx.x;
    for (int i = t; i < SSZ; i += 1024) { sv[i] = v[i]; sc[i] = cnt[i]; }
    __syncthreads();
    for (int i = t; i < SSZ; i += 1024) {
        const unsigned short* cl = cols + (size_t)i * CSTR;
        int n = sc[i];
        float s = 0.0f;
        for (int k = 0; k < n; ++k) s += sv[cl[k]];
        s1[i] = s;
    }
    __syncthreads();
    for (int i = t; i < SSZ; i += 1024) {
        const unsigned short* cl = cols + (size_t)i * CSTR;
        int n = sc[i];
        float s = 0.0f;
        for (int k = 0; k < n; ++k) s += s1[cl[k]];
        s2[i] = s + ib[0];
    }
    __syncthreads();
    float s = 0.0f;
    for (int i = t; i < SSZ; i += 1024) s += fabsf(s2[i]);
#pragma unroll
    for (int o = 32; o > 0; o >>= 1) s += __shfl_down(s, o, 64);
    if ((t & 63) == 0) wsum[t >> 6] = s;
    __syncthreads();
    if (t == 0) {
        float tot = 0.0f;
#pragma unroll
        for (int k = 0; k < 16; ++k) tot += wsum[k];
        inv = 1.0f / fmaxf(tot, 1e-12f);
    }
    __syncthreads();
    for (int i = t; i < NEIGH; i += 1024) out[i] = s2[NACT + i] * inv;
}

// --------------------------------------------------------------------------
extern "C" void kernel_launch(void* const* d_in, const int* in_sizes, int n_in,
                              void* d_out, int out_size, void* d_ws, size_t ws_size,
                              hipStream_t stream) {
    const float* x   = (const float*)d_in[0];
    const float* adj = (const float*)d_in[1];
    const int*   act = (const int*)d_in[2];
    const int*   nb  = (const int*)d_in[3];
    const float* W1  = (const float*)d_in[4];
    const float* W2  = (const float*)d_in[5];
    const float* iw  = (const float*)d_in[6];
    const float* ib  = (const float*)d_in[7];
    float* out = (float*)d_out;

    // workspace layout (bytes, 256-aligned) — total ~4.6 MB
    char* ws = (char*)d_ws;
    int*            cur  = (int*)           (ws + 0);        // 8448 B
    int*            cnt  = (int*)           (ws + 8704);     // 8448 B
    unsigned short* cols = (unsigned short*)(ws + 17408);    // 264 KB
    float*          B1   = (float*)         (ws + 287744);   // 4.33 MB
    float*          u    = (float*)         (ws + 4613120);  // 2 KB
    float*          v    = (float*)         (ws + 4615168);  // 8448 B

    k_scan <<<dim3(SSZ),   256,  0, stream>>>(adj, act, nb, W2, iw,
                                              cnt, cols, cur, u, out + NEIGH);
    k_gemm <<<dim3(66, 8), 256,  0, stream>>>(x, W1, B1, SSZ, NHID, NFEAT, cur);
    k_spmv <<<dim3(SSZ),   256,  0, stream>>>(B1, cnt, cols, u, v);
    k_final<<<dim3(1),     1024, 0, stream>>>(cnt, cols, v, ib, out);
}